// Round 11
// baseline (764.647 us; speedup 1.0000x reference)
//
#include <hip/hip_runtime.h>
#include <hip/hip_cooperative_groups.h>
#include <math.h>

namespace cg = cooperative_groups;

#define N_NODES 1024
#define EDGE    4
#define DIM     64
#define ANND    16
#define STEPS   5
#define BATCH   4

typedef __attribute__((ext_vector_type(8))) short bf16x8;
typedef __attribute__((ext_vector_type(4))) float f32x4;

__device__ __forceinline__ float fsigmoid(float x) {
    return 1.0f / (1.0f + __expf(-x));
}
__device__ __forceinline__ float ftanh(float x) {
    x = fminf(15.0f, fmaxf(-15.0f, x));
    float t = __expf(2.0f * x);
    return (t - 1.0f) / (t + 1.0f);
}
__device__ __forceinline__ unsigned short f32_to_bf16(float x) {
    unsigned int u = __float_as_uint(x);
    unsigned int r = u + 0x7FFFu + ((u >> 16) & 1u);
    return (unsigned short)(r >> 16);
}

// ---------------------------------------------------------------------------
// Monolithic cooperative kernel: 256 blocks x 256 threads, 1 block/CU.
// LDS: wl (96 KB, gate weights, persists across steps) + scratch (16.9 KB,
// multi-use: transpose tile / gemm X-tiles / gate activations / outk o1hT).
// Phases separated by grid.sync(): prep -> 5x(gemm, gate) -> outk.
// R8 fix vs R7: outk stages all 4096 elements of o1hT (was 1024 -> 3/4 of
// the output-head weights were stale LDS garbage -> absmax 0.397).
// ---------------------------------------------------------------------------
__global__ __launch_bounds__(256) void ggnn_mono(
    const float* __restrict__ prop, const float* __restrict__ ann,
    const float* __restrict__ A,
    const float* __restrict__ inW, const float* __restrict__ inb,
    const float* __restrict__ rW, const float* __restrict__ rb,
    const float* __restrict__ zW, const float* __restrict__ zb,
    const float* __restrict__ hW, const float* __restrict__ hb,
    const float* __restrict__ o1W, const float* __restrict__ o1b,
    const float* __restrict__ o2W, const float* __restrict__ o2b,
    float* __restrict__ out, char* __restrict__ ws)
{
    // workspace layout
    float* h_ws   = (float*)ws;                       // 262144
    float* part   = h_ws + 262144;                    // 16*65536 = 1048576
    float* wcomb  = part + 1048576;                   // 24576
    float* w1s    = wcomb + 24576;                    // 256
    float* o1hT   = w1s + 256;                        // 4096
    float* o1aT   = o1hT + 4096;                      // 1024
    float* rowsum = o1aT + 1024;                      // 16384
    unsigned short* Ahl  = (unsigned short*)(rowsum + 16384);  // 33554432
    unsigned short* hThi = Ahl + (size_t)33554432;             // 262144
    unsigned short* hTlo = hThi + 262144;                      // 262144

    __shared__ float wl[24576];       // 96 KB — persists all steps
    __shared__ float scratch[4224];   // 16.9 KB — phase-multiplexed

    const int bid  = blockIdx.x;      // 0..255
    const int tid  = threadIdx.x;
    const int lane = tid & 63, wave = tid >> 6;
    cg::grid_group grid = cg::this_grid();

    // ---------------- P0: prep --------------------------------------------
    // transpose of prop -> hThi/hTlo (blocks 0..63, uses scratch + barriers)
    if (bid < 64) {
        float (*tile)[65] = (float(*)[65])scratch;
        const int bm = bid & 15, tb = bid >> 4;
        {
            const int mml = tid >> 2, d0 = (tid & 3) * 16;
            const float* src = prop + ((size_t)(tb * 1024 + bm * 64 + mml)) * 64 + d0;
#pragma unroll
            for (int i = 0; i < 4; ++i) {
                float4 v = *(const float4*)(src + i * 4);
                tile[d0 + i * 4 + 0][mml] = v.x;
                tile[d0 + i * 4 + 1][mml] = v.y;
                tile[d0 + i * 4 + 2][mml] = v.z;
                tile[d0 + i * 4 + 3][mml] = v.w;
            }
        }
        __syncthreads();
        const int d = tid >> 2, m0 = (tid & 3) * 16;
        alignas(16) unsigned short hb16[16], lb16[16];
#pragma unroll
        for (int i = 0; i < 16; ++i) {
            float x = tile[d][m0 + i];
            unsigned short hh = f32_to_bf16(x);
            hb16[i] = hh;
            lb16[i] = f32_to_bf16(x - __uint_as_float((unsigned int)hh << 16));
        }
        unsigned short* dst = hThi + ((size_t)(tb * 64 + d)) * 1024 + bm * 64 + m0;
        *(uint4*)dst = *(const uint4*)&hb16[0];
        *(uint4*)(dst + 8) = *(const uint4*)&hb16[8];
        unsigned short* dstl = hTlo + ((size_t)(tb * 64 + d)) * 1024 + bm * 64 + m0;
        *(uint4*)dstl = *(const uint4*)&lb16[0];
        *(uint4*)(dstl + 8) = *(const uint4*)&lb16[8];
    }

    // prepW: w1s / wcomb / o1hT / o1aT  (29952 items over blocks 0..116)
    {
        int id = bid * 256 + tid;
        if (id < 256) {
            int e = id >> 6, d = id & 63;
            float s = 0.0f;
            for (int f = 0; f < 64; ++f) s += inW[(e * 64 + f) * 64 + d];
            w1s[id] = s;
        }
        int i1 = id - 256;
        if (i1 >= 0 && i1 < 24576) {
            int mat = i1 >> 12, rem = i1 & 4095, d = rem >> 6, j = rem & 63;
            const float* W = (mat < 2) ? rW : (mat < 4) ? zW : hW;
            float v;
            if ((mat & 1) == 0) v = W[j * 192 + d] + W[j * 192 + 64 + d];
            else                v = W[j * 192 + 128 + d];
            wcomb[mat * 4096 + d * 64 + j] = v;
        }
        int i2 = id - 256 - 24576;
        if (i2 >= 0 && i2 < 4096) {
            int d = i2 >> 6, j = i2 & 63;
            o1hT[d * 64 + j] = o1W[j * 80 + d];
        }
        int i3 = id - 256 - 24576 - 4096;
        if (i3 >= 0 && i3 < 1024) {
            int a = i3 >> 6, j = i3 & 63;
            o1aT[a * 64 + j] = o1W[j * 80 + 64 + a];
        }
    }

    // h copy: prop -> h_ws (1 MB over all blocks)
    {
        int base = bid * 1024 + tid * 4;
        *(float4*)&h_ws[base] = *(const float4*)&prop[base];
    }

    // prepA: 16 rows per block; f32 -> hi/lo-interleaved bf16 + rowsums
    {
        const float* srcb = A + (size_t)bid * 16 * 8192 + tid * 16;
        unsigned short* dstb = Ahl + (size_t)bid * 16 * 8192 + tid * 32;
        for (int r = 0; r < 16; ++r) {
            const float* src = srcb + (size_t)r * 8192;
            unsigned short* dst = dstb + (size_t)r * 8192;
            float s = 0.f;
#pragma unroll
            for (int c = 0; c < 2; ++c) {
                alignas(16) unsigned short hs[8], ls[8];
#pragma unroll
                for (int i = 0; i < 2; ++i) {
                    float4 v = *(const float4*)(src + c * 8 + i * 4);
                    float vv[4] = {v.x, v.y, v.z, v.w};
#pragma unroll
                    for (int j = 0; j < 4; ++j) {
                        float x = vv[j];
                        s += x;
                        unsigned short hh = f32_to_bf16(x);
                        hs[i * 4 + j] = hh;
                        ls[i * 4 + j] = f32_to_bf16(x - __uint_as_float((unsigned int)hh << 16));
                    }
                }
                *(uint4*)(dst + c * 16)     = *(const uint4*)hs;
                *(uint4*)(dst + c * 16 + 8) = *(const uint4*)ls;
            }
#pragma unroll
            for (int off = 32; off > 0; off >>= 1) s += __shfl_down(s, off);
            if (lane == 0) rowsum[(size_t)(bid * 16 + r) * 4 + wave] = s;
        }
    }

    grid.sync();

    // stage gate weights into LDS once (persist across all 5 steps)
#pragma unroll
    for (int i = 0; i < 24; ++i) {
        int idx = i * 256 + tid;
        *(float4*)&wl[idx * 4] = *(const float4*)&wcomb[idx * 4];
    }
    __syncthreads();

    // ---------------- step loop -------------------------------------------
    for (int s = 0; s < STEPS; ++s) {
        // ---- gemm phase: block = (nb = bid>>4, e = (bid>>2)&3, b = bid&3)
        {
            unsigned short* Xh = (unsigned short*)scratch;   // [64][64]
            unsigned short* Xl = Xh + 4096;
            const int gb = bid & 3, ge = (bid >> 2) & 3, gnb = bid >> 4;
            const int rowbase = gnb * 64 + wave * 16;
            const size_t abase = ((size_t)(gb * 1024 + rowbase + (lane & 15))) * 8192
                               + (size_t)(ge * 128 + (lane >> 4)) * 16;
            const int sd = tid >> 3, sc = tid & 7;
            const int scp = (sc ^ (sd & 7)) * 8;
            const int ldsoff0 = sd * 64 + scp;
            const int ldsoff1 = (sd + 32) * 64 + scp;
            const size_t xsrc = ((size_t)(gb * 64 + sd)) * 1024 + sc * 8;
            const unsigned short* xh0 = hThi + xsrc;
            const unsigned short* xl0 = hTlo + xsrc;

            uint4 sH0 = *(const uint4*)(xh0);
            uint4 sH1 = *(const uint4*)(xh0 + 32 * 1024);
            uint4 sL0 = *(const uint4*)(xl0);
            uint4 sL1 = *(const uint4*)(xl0 + 32 * 1024);

            f32x4 acc[4] = {};

            for (int sub = 0; sub < 16; ++sub) {
                __syncthreads();
                *(uint4*)&Xh[ldsoff0] = sH0;
                *(uint4*)&Xh[ldsoff1] = sH1;
                *(uint4*)&Xl[ldsoff0] = sL0;
                *(uint4*)&Xl[ldsoff1] = sL1;
                __syncthreads();
                if (sub < 15) {
                    const unsigned short* ph = xh0 + (sub + 1) * 64;
                    const unsigned short* pl = xl0 + (sub + 1) * 64;
                    sH0 = *(const uint4*)(ph);
                    sH1 = *(const uint4*)(ph + 32 * 1024);
                    sL0 = *(const uint4*)(pl);
                    sL1 = *(const uint4*)(pl + 32 * 1024);
                }
#pragma unroll
                for (int ks = 0; ks < 2; ++ks) {
                    const unsigned short* ap = Ahl + abase + (size_t)(sub * 8 + ks * 4) * 16;
                    bf16x8 a_hi = *(const bf16x8*)(ap);
                    bf16x8 a_lo = *(const bf16x8*)(ap + 8);
#pragma unroll
                    for (int df = 0; df < 4; ++df) {
                        const int d = df * 16 + (lane & 15);
                        const int cp = (((ks * 4) + (lane >> 4)) ^ (d & 7)) * 8;
                        bf16x8 xh = *(const bf16x8*)&Xh[d * 64 + cp];
                        bf16x8 xl = *(const bf16x8*)&Xl[d * 64 + cp];
                        acc[df] = __builtin_amdgcn_mfma_f32_16x16x32_bf16(a_hi, xh, acc[df], 0, 0, 0);
                        acc[df] = __builtin_amdgcn_mfma_f32_16x16x32_bf16(a_hi, xl, acc[df], 0, 0, 0);
                        acc[df] = __builtin_amdgcn_mfma_f32_16x16x32_bf16(a_lo, xh, acc[df], 0, 0, 0);
                    }
                }
            }

            float* pbase = part + ((size_t)(ge * 4 + gb)) * 65536;
#pragma unroll
            for (int df = 0; df < 4; ++df) {
                const int d = df * 16 + (lane & 15);
                const float w = w1s[ge * 64 + d];
#pragma unroll
                for (int r = 0; r < 4; ++r) {
                    int n = rowbase + (lane >> 4) * 4 + r;
                    pbase[(size_t)n * 64 + d] = acc[df][r] * w;
                }
            }
        }
        grid.sync();

        // ---- gate phase: 16 nodes per block, weights already in LDS ----
        {
            float* ain  = scratch;          // [16][64]
            float* hsh  = scratch + 1024;
            float* rsh  = scratch + 2048;
            float* hnsh = scratch + 3072;
            const int nodeBase = bid * 16;

#pragma unroll
            for (int i = 0; i < 4; ++i) {
                int idx = tid + 256 * i;
                int nl = idx >> 6, d = idx & 63;
                int node = nodeBase + nl;
                int bb = node >> 10, n = node & 1023;
                const float* pp = part + (size_t)bb * 65536 + (size_t)n * 64 + d;
                float sv = pp[0] + pp[262144] + pp[2 * 262144] + pp[3 * 262144];
                const float* rs = rowsum + (size_t)node * 4;
#pragma unroll
                for (int e = 0; e < 4; ++e) sv += rs[e] * inb[e * 64 + d];
                ain[nl * 64 + d] = sv;
                hsh[nl * 64 + d] = h_ws[(size_t)node * 64 + d];
            }
            __syncthreads();

            const int j  = tid & 63;
            const int ng = tid >> 6;
            const float* rCT = wl;
            const float* rHT = wl + 4096;
            const float* zCT = wl + 8192;
            const float* zHT = wl + 12288;
            const float* hCT = wl + 16384;
            const float* hHT = wl + 20480;

            float accr[4], accz[4];
#pragma unroll
            for (int i = 0; i < 4; ++i) { accr[i] = rb[j]; accz[i] = zb[j]; }
            for (int d = 0; d < 64; ++d) {
                float wrc = rCT[d * 64 + j], wrh = rHT[d * 64 + j];
                float wzc = zCT[d * 64 + j], wzh = zHT[d * 64 + j];
#pragma unroll
                for (int i = 0; i < 4; ++i) {
                    int nl = ng * 4 + i;
                    float av = ain[nl * 64 + d], hv = hsh[nl * 64 + d];
                    accr[i] = fmaf(av, wrc, accr[i]); accr[i] = fmaf(hv, wrh, accr[i]);
                    accz[i] = fmaf(av, wzc, accz[i]); accz[i] = fmaf(hv, wzh, accz[i]);
                }
            }
            float zreg[4];
#pragma unroll
            for (int i = 0; i < 4; ++i) {
                int nl = ng * 4 + i;
                rsh[nl * 64 + j] = fsigmoid(accr[i]);
                zreg[i] = fsigmoid(accz[i]);
            }
            __syncthreads();

            float acch[4];
#pragma unroll
            for (int i = 0; i < 4; ++i) acch[i] = hb[j];
            for (int d = 0; d < 64; ++d) {
                float whc = hCT[d * 64 + j], whh = hHT[d * 64 + j];
#pragma unroll
                for (int i = 0; i < 4; ++i) {
                    int nl = ng * 4 + i;
                    float av = ain[nl * 64 + d];
                    float rh = rsh[nl * 64 + d] * hsh[nl * 64 + d];
                    acch[i] = fmaf(av, whc, acch[i]); acch[i] = fmaf(rh, whh, acch[i]);
                }
            }
#pragma unroll
            for (int i = 0; i < 4; ++i) {
                int nl = ng * 4 + i;
                int node = nodeBase + nl;
                float hh2 = ftanh(acch[i]);
                float ho = hsh[nl * 64 + j];
                float hnew = ho + zreg[i] * (hh2 - ho);
                h_ws[(size_t)node * 64 + j] = hnew;
                hnsh[nl * 64 + j] = hnew;
            }
            __syncthreads();

            // transposed bf16 hi/lo write for next step's gemm
            {
                const int d = tid >> 2, q = tid & 3;
                const int bb = nodeBase >> 10;
                const int mm0 = (nodeBase & 1023) + q * 4;
                alignas(8) unsigned short hb4[4], lb4[4];
#pragma unroll
                for (int i = 0; i < 4; ++i) {
                    float x = hnsh[(q * 4 + i) * 64 + d];
                    unsigned short hh = f32_to_bf16(x);
                    hb4[i] = hh;
                    lb4[i] = f32_to_bf16(x - __uint_as_float((unsigned int)hh << 16));
                }
                unsigned short* dst = hThi + ((size_t)(bb * 64 + d)) * 1024 + mm0;
                *(uint2*)dst = *(const uint2*)hb4;
                unsigned short* dstl = hTlo + ((size_t)(bb * 64 + d)) * 1024 + mm0;
                *(uint2*)dstl = *(const uint2*)lb4;
            }
        }
        grid.sync();
    }

    // ---------------- outk: output head, 16 nodes per block ---------------
    {
        // full o1hT (4096 floats) into scratch — R7 bug was staging only 1024
#pragma unroll
        for (int i = 0; i < 16; ++i) {
            int idx = tid + 256 * i;
            scratch[idx] = o1hT[idx];   // [64 d][64 j]
        }
#pragma unroll
        for (int i = 0; i < 4; ++i) {
            int idx = tid + 256 * i;
            wl[idx] = o1aT[idx];        // [16 a][64 j]
        }
        if (tid < 64) { wl[4096 + tid] = o1b[tid]; wl[4160 + tid] = o2W[tid]; }
        __syncthreads();
        const int j = lane;
#pragma unroll
        for (int i = 0; i < 4; ++i) {
            int node = bid * 16 + wave * 4 + i;
            float acc2 = wl[4096 + j];
            const float* hp = h_ws + (size_t)node * 64;
            for (int d = 0; d < 64; ++d) acc2 = fmaf(hp[d], scratch[d * 64 + j], acc2);
            const float* ap2 = ann + (size_t)node * 16;
#pragma unroll
            for (int a = 0; a < 16; ++a) acc2 = fmaf(ap2[a], wl[a * 64 + j], acc2);
            float t = ftanh(acc2) * wl[4160 + j];
#pragma unroll
            for (int off = 32; off > 0; off >>= 1) t += __shfl_down(t, off);
            if (j == 0) out[node] = t + o2b[0];
        }
    }
}

// ---------------------------------------------------------------------------
extern "C" void kernel_launch(void* const* d_in, const int* in_sizes, int n_in,
                              void* d_out, int out_size, void* d_ws, size_t ws_size,
                              hipStream_t stream)
{
    (void)in_sizes; (void)n_in; (void)out_size; (void)ws_size;
    const float* prop = (const float*)d_in[0];
    const float* ann  = (const float*)d_in[1];
    const float* A    = (const float*)d_in[2];
    const float* inW  = (const float*)d_in[3];
    const float* inb  = (const float*)d_in[4];
    // d_in[5] out_W, d_in[6] out_b unused (a_out = a_in in the reference)
    const float* rW   = (const float*)d_in[7];
    const float* rb   = (const float*)d_in[8];
    const float* zW   = (const float*)d_in[9];
    const float* zb   = (const float*)d_in[10];
    const float* hW   = (const float*)d_in[11];
    const float* hb   = (const float*)d_in[12];
    const float* o1W  = (const float*)d_in[13];
    const float* o1b  = (const float*)d_in[14];
    const float* o2W  = (const float*)d_in[15];
    const float* o2b  = (const float*)d_in[16];
    float* out = (float*)d_out;
    char* ws = (char*)d_ws;

    void* args[] = {
        &prop, &ann, &A, &inW, &inb, &rW, &rb, &zW, &zb, &hW, &hb,
        &o1W, &o1b, &o2W, &o2b, &out, &ws
    };
    hipLaunchCooperativeKernel((const void*)ggnn_mono, dim3(256), dim3(256),
                               args, 0, stream);
}

// Round 14
// 435.109 us; speedup vs baseline: 1.7574x; 1.7574x over previous
//
#include <hip/hip_runtime.h>
#include <math.h>

#define N_NODES 1024
#define EDGE    4
#define DIM     64
#define ANND    16
#define STEPS   5
#define BATCH   4

typedef __attribute__((ext_vector_type(8))) short bf16x8;
typedef __attribute__((ext_vector_type(4))) float f32x4;

__device__ __forceinline__ float fsigmoid(float x) {
    return 1.0f / (1.0f + __expf(-x));
}
__device__ __forceinline__ float ftanh(float x) {
    x = fminf(15.0f, fmaxf(-15.0f, x));
    float t = __expf(2.0f * x);
    return (t - 1.0f) / (t + 1.0f);
}
__device__ __forceinline__ unsigned short f32_to_bf16(float x) {
    unsigned int u = __float_as_uint(x);
    unsigned int r = u + 0x7FFFu + ((u >> 16) & 1u);
    return (unsigned short)(r >> 16);
}

// ---------------------------------------------------------------------------
// prep: merged prepA (1 A-row per block, hi/lo-interleaved bf16 + rowsums) +
// transposeH (bids 0..63) + prepW (bids 0..116) + h-copy (bids 0..255).
// Grid 4096 x 256.
// ---------------------------------------------------------------------------
__global__ __launch_bounds__(256) void prep(
    const float* __restrict__ A, const float* __restrict__ prop,
    const float* __restrict__ inW,
    const float* __restrict__ rW, const float* __restrict__ zW,
    const float* __restrict__ hW, const float* __restrict__ o1W,
    unsigned short* __restrict__ Ahl, float* __restrict__ rowsum,
    float* __restrict__ h_ws,
    unsigned short* __restrict__ hThi, unsigned short* __restrict__ hTlo,
    float* __restrict__ wcomb, float* __restrict__ w1s,
    float* __restrict__ o1hT, float* __restrict__ o1aT)
{
    __shared__ float tile[64][65];
    const int bid = blockIdx.x, tid = threadIdx.x;
    const int lane = tid & 63, wave = tid >> 6;

    // ---- prepA: row = bid (first 4096 cols = A_in) ----
    {
        const float* src = A + (size_t)bid * 8192 + tid * 16;
        unsigned short* dst = Ahl + (size_t)bid * 8192 + tid * 32;
        float s = 0.f;
#pragma unroll
        for (int c = 0; c < 2; ++c) {
            alignas(16) unsigned short hs[8], ls[8];
#pragma unroll
            for (int i = 0; i < 2; ++i) {
                float4 v = *(const float4*)(src + c * 8 + i * 4);
                float vv[4] = {v.x, v.y, v.z, v.w};
#pragma unroll
                for (int j = 0; j < 4; ++j) {
                    float x = vv[j];
                    s += x;
                    unsigned short hh = f32_to_bf16(x);
                    hs[i * 4 + j] = hh;
                    ls[i * 4 + j] = f32_to_bf16(x - __uint_as_float((unsigned int)hh << 16));
                }
            }
            *(uint4*)(dst + c * 16)     = *(const uint4*)hs;
            *(uint4*)(dst + c * 16 + 8) = *(const uint4*)ls;
        }
#pragma unroll
        for (int off = 32; off > 0; off >>= 1) s += __shfl_down(s, off);
        if (lane == 0) rowsum[(size_t)bid * 4 + wave] = s;
    }

    // ---- transposeH: prop -> hThi/hTlo (buffer 0), bids 0..63 ----
    if (bid < 64) {
        const int bm = bid & 15, tb = bid >> 4;
        {
            const int mml = tid >> 2, d0 = (tid & 3) * 16;
            const float* src = prop + ((size_t)(tb * 1024 + bm * 64 + mml)) * 64 + d0;
#pragma unroll
            for (int i = 0; i < 4; ++i) {
                float4 v = *(const float4*)(src + i * 4);
                tile[d0 + i * 4 + 0][mml] = v.x;
                tile[d0 + i * 4 + 1][mml] = v.y;
                tile[d0 + i * 4 + 2][mml] = v.z;
                tile[d0 + i * 4 + 3][mml] = v.w;
            }
        }
        __syncthreads();
        const int d = tid >> 2, m0 = (tid & 3) * 16;
        alignas(16) unsigned short hb16[16], lb16[16];
#pragma unroll
        for (int i = 0; i < 16; ++i) {
            float x = tile[d][m0 + i];
            unsigned short hh = f32_to_bf16(x);
            hb16[i] = hh;
            lb16[i] = f32_to_bf16(x - __uint_as_float((unsigned int)hh << 16));
        }
        unsigned short* dst = hThi + ((size_t)(tb * 64 + d)) * 1024 + bm * 64 + m0;
        *(uint4*)dst = *(const uint4*)&hb16[0];
        *(uint4*)(dst + 8) = *(const uint4*)&hb16[8];
        unsigned short* dstl = hTlo + ((size_t)(tb * 64 + d)) * 1024 + bm * 64 + m0;
        *(uint4*)dstl = *(const uint4*)&lb16[0];
        *(uint4*)(dstl + 8) = *(const uint4*)&lb16[8];
    }

    // ---- prepW: w1s / wcomb / o1hT / o1aT ----
    {
        int id = bid * 256 + tid;
        if (id < 256) {
            int e = id >> 6, d = id & 63;
            float s = 0.0f;
            for (int f = 0; f < 64; ++f) s += inW[(e * 64 + f) * 64 + d];
            w1s[id] = s;
        }
        int i1 = id - 256;
        if (i1 >= 0 && i1 < 24576) {
            int mat = i1 >> 12, rem = i1 & 4095, d = rem >> 6, j = rem & 63;
            const float* W = (mat < 2) ? rW : (mat < 4) ? zW : hW;
            float v;
            if ((mat & 1) == 0) v = W[j * 192 + d] + W[j * 192 + 64 + d];
            else                v = W[j * 192 + 128 + d];
            wcomb[mat * 4096 + d * 64 + j] = v;
        }
        int i2 = id - 256 - 24576;
        if (i2 >= 0 && i2 < 4096) {
            int d = i2 >> 6, j = i2 & 63;
            o1hT[d * 64 + j] = o1W[j * 80 + d];
        }
        int i3 = id - 256 - 24576 - 4096;
        if (i3 >= 0 && i3 < 1024) {
            int a = i3 >> 6, j = i3 & 63;
            o1aT[a * 64 + j] = o1W[j * 80 + 64 + a];
        }
    }

    // ---- h copy: prop -> h_ws ----
    if (bid < 256) {
        int base = bid * 1024 + tid * 4;
        *(float4*)&h_ws[base] = *(const float4*)&prop[base];
    }
}

// ---------------------------------------------------------------------------
// step_k: fused gemm+gate for one propagation step.
// Grid (64 nblk, 4 b) = 256 blocks x 256 thr. Block = 16 rows; wave w = edge w
// (all waves share the X LDS tiles; A_e indexes the same m-space for every e).
// 3-pass split-bf16 MFMA; per-e acc scaled by W1s -> LDS partial -> summed
// a_in -> GRU gate -> h + double-buffered hT write. last!=0 also runs outk.
// ---------------------------------------------------------------------------
__global__ __launch_bounds__(256) void step_k(
    const unsigned short* __restrict__ Ahl,
    const unsigned short* __restrict__ hThiR, const unsigned short* __restrict__ hTloR,
    const float* __restrict__ w1s, const float* __restrict__ rowsum,
    const float* __restrict__ inb, const float* __restrict__ wcomb,
    const float* __restrict__ rb, const float* __restrict__ zb,
    const float* __restrict__ hbias, float* __restrict__ h_ws,
    unsigned short* __restrict__ hThiW, unsigned short* __restrict__ hTloW,
    const float* __restrict__ ann, const float* __restrict__ o1hT,
    const float* __restrict__ o1aT, const float* __restrict__ o1b,
    const float* __restrict__ o2W, const float* __restrict__ o2b,
    float* __restrict__ out, int last)
{
    __shared__ unsigned short Xh[4096];      // [64 d][64 m] swizzled
    __shared__ unsigned short Xl[4096];
    __shared__ float partial[4][16][64];     // per-edge scaled contributions
    __shared__ float ain[16][64];
    __shared__ float hsh[16][64];
    __shared__ float rsh[16][64];
    __shared__ float hnsh[16][64];

    const int tid = threadIdx.x;
    const int lane = tid & 63, wave = tid >> 6;
    const int nblk = blockIdx.x, b = blockIdx.y;
    const int rowbase = nblk * 16;
    const int nodeBase = b * 1024 + rowbase;

    // A fragment base: rows rowbase+(lane&15), edge = wave.
    // Ahl row layout: 512 groups of 16 ushort (8 hi | 8 lo); group g covers
    // elems 8g..8g+7. g = wave*128 + sub*8 + ks*4 + (lane>>4).
    const size_t abase = ((size_t)(b * 1024 + rowbase + (lane & 15))) * 8192
                       + (size_t)(wave * 128 + (lane >> 4)) * 16;

    // X staging (identical to verified r6 pattern): sd = d-row, sc = 16B chunk
    const int sd = tid >> 3, sc = tid & 7;
    const int scp = (sc ^ (sd & 7)) * 8;
    const int ldsoff0 = sd * 64 + scp;
    const int ldsoff1 = (sd + 32) * 64 + scp;
    const size_t xsrc = ((size_t)(b * 64 + sd)) * 1024 + sc * 8;
    const unsigned short* xh0 = hThiR + xsrc;
    const unsigned short* xl0 = hTloR + xsrc;

    uint4 sH0 = *(const uint4*)(xh0);
    uint4 sH1 = *(const uint4*)(xh0 + 32 * 1024);
    uint4 sL0 = *(const uint4*)(xl0);
    uint4 sL1 = *(const uint4*)(xl0 + 32 * 1024);

    // A prefetch (one sub ahead): explicit named regs (rule #20)
    bf16x8 pa_hi0, pa_lo0, pa_hi1, pa_lo1;
    {
        const unsigned short* ap0 = Ahl + abase;
        pa_hi0 = *(const bf16x8*)(ap0);
        pa_lo0 = *(const bf16x8*)(ap0 + 8);
        const unsigned short* ap1 = Ahl + abase + 64;   // ks=1: +4 groups
        pa_hi1 = *(const bf16x8*)(ap1);
        pa_lo1 = *(const bf16x8*)(ap1 + 8);
    }

    f32x4 acc[4] = {};

    for (int sub = 0; sub < 16; ++sub) {
        __syncthreads();
        *(uint4*)&Xh[ldsoff0] = sH0;
        *(uint4*)&Xh[ldsoff1] = sH1;
        *(uint4*)&Xl[ldsoff0] = sL0;
        *(uint4*)&Xl[ldsoff1] = sL1;
        __syncthreads();

        bf16x8 ca_hi0 = pa_hi0, ca_lo0 = pa_lo0;
        bf16x8 ca_hi1 = pa_hi1, ca_lo1 = pa_lo1;

        if (sub < 15) {
            const unsigned short* ph = xh0 + (sub + 1) * 64;
            const unsigned short* pl = xl0 + (sub + 1) * 64;
            sH0 = *(const uint4*)(ph);
            sH1 = *(const uint4*)(ph + 32 * 1024);
            sL0 = *(const uint4*)(pl);
            sL1 = *(const uint4*)(pl + 32 * 1024);
            const unsigned short* ap0 = Ahl + abase + (size_t)((sub + 1) * 8) * 16;
            pa_hi0 = *(const bf16x8*)(ap0);
            pa_lo0 = *(const bf16x8*)(ap0 + 8);
            const unsigned short* ap1 = ap0 + 64;
            pa_hi1 = *(const bf16x8*)(ap1);
            pa_lo1 = *(const bf16x8*)(ap1 + 8);
        }

#pragma unroll
        for (int df = 0; df < 4; ++df) {
            const int d = df * 16 + (lane & 15);
            const int cp0 = (((lane >> 4)) ^ (d & 7)) * 8;
            const int cp1 = (((4 + (lane >> 4))) ^ (d & 7)) * 8;
            bf16x8 xh_0 = *(const bf16x8*)&Xh[d * 64 + cp0];
            bf16x8 xl_0 = *(const bf16x8*)&Xl[d * 64 + cp0];
            acc[df] = __builtin_amdgcn_mfma_f32_16x16x32_bf16(ca_hi0, xh_0, acc[df], 0, 0, 0);
            acc[df] = __builtin_amdgcn_mfma_f32_16x16x32_bf16(ca_hi0, xl_0, acc[df], 0, 0, 0);
            acc[df] = __builtin_amdgcn_mfma_f32_16x16x32_bf16(ca_lo0, xh_0, acc[df], 0, 0, 0);
            bf16x8 xh_1 = *(const bf16x8*)&Xh[d * 64 + cp1];
            bf16x8 xl_1 = *(const bf16x8*)&Xl[d * 64 + cp1];
            acc[df] = __builtin_amdgcn_mfma_f32_16x16x32_bf16(ca_hi1, xh_1, acc[df], 0, 0, 0);
            acc[df] = __builtin_amdgcn_mfma_f32_16x16x32_bf16(ca_hi1, xl_1, acc[df], 0, 0, 0);
            acc[df] = __builtin_amdgcn_mfma_f32_16x16x32_bf16(ca_lo1, xh_1, acc[df], 0, 0, 0);
        }
    }

    // scale by W1s[e=wave][d], deposit into LDS partial.
    // C/D layout: col = lane&15, row_local = (lane>>4)*4 + r.
#pragma unroll
    for (int df = 0; df < 4; ++df) {
        const int d = df * 16 + (lane & 15);
        const float w = w1s[wave * 64 + d];
#pragma unroll
        for (int r = 0; r < 4; ++r)
            partial[wave][(lane >> 4) * 4 + r][d] = acc[df][r] * w;
    }
    __syncthreads();

    // a_in = sum over edges + rowsum*inb; load old h
#pragma unroll
    for (int i = 0; i < 4; ++i) {
        int idx = tid + 256 * i;
        int nl = idx >> 6, d = idx & 63;
        int node = nodeBase + nl;
        float sv = partial[0][nl][d] + partial[1][nl][d]
                 + partial[2][nl][d] + partial[3][nl][d];
        const float* rs = rowsum + (size_t)node * 4;
#pragma unroll
        for (int e = 0; e < 4; ++e) sv += rs[e] * inb[e * 64 + d];
        ain[nl][d] = sv;
        hsh[nl][d] = h_ws[(size_t)node * 64 + d];
    }
    __syncthreads();

    // ---- gate (verified r6 structure; weights from global, L2-hot) ----
    const int j  = tid & 63;
    const int ng = wave;
    const float* rCT = wcomb;
    const float* rHT = wcomb + 4096;
    const float* zCT = wcomb + 8192;
    const float* zHT = wcomb + 12288;
    const float* hCT = wcomb + 16384;
    const float* hHT = wcomb + 20480;

    float accr[4], accz[4];
#pragma unroll
    for (int i = 0; i < 4; ++i) { accr[i] = rb[j]; accz[i] = zb[j]; }
    for (int d = 0; d < 64; ++d) {
        float wrc = rCT[d * 64 + j], wrh = rHT[d * 64 + j];
        float wzc = zCT[d * 64 + j], wzh = zHT[d * 64 + j];
#pragma unroll
        for (int i = 0; i < 4; ++i) {
            int nl = ng * 4 + i;
            float av = ain[nl][d], hv = hsh[nl][d];
            accr[i] = fmaf(av, wrc, accr[i]); accr[i] = fmaf(hv, wrh, accr[i]);
            accz[i] = fmaf(av, wzc, accz[i]); accz[i] = fmaf(hv, wzh, accz[i]);
        }
    }
    float zreg[4];
#pragma unroll
    for (int i = 0; i < 4; ++i) {
        int nl = ng * 4 + i;
        rsh[nl][j] = fsigmoid(accr[i]);
        zreg[i] = fsigmoid(accz[i]);
    }
    __syncthreads();

    float acch[4];
#pragma unroll
    for (int i = 0; i < 4; ++i) acch[i] = hbias[j];
    for (int d = 0; d < 64; ++d) {
        float whc = hCT[d * 64 + j], whh = hHT[d * 64 + j];
#pragma unroll
        for (int i = 0; i < 4; ++i) {
            int nl = ng * 4 + i;
            float av = ain[nl][d];
            float rh = rsh[nl][d] * hsh[nl][d];
            acch[i] = fmaf(av, whc, acch[i]); acch[i] = fmaf(rh, whh, acch[i]);
        }
    }
#pragma unroll
    for (int i = 0; i < 4; ++i) {
        int nl = ng * 4 + i;
        int node = nodeBase + nl;
        float hh2 = ftanh(acch[i]);
        float ho = hsh[nl][j];
        float hnew = ho + zreg[i] * (hh2 - ho);
        h_ws[(size_t)node * 64 + j] = hnew;
        hnsh[nl][j] = hnew;
    }
    __syncthreads();

    // transposed bf16 hi/lo write into the WRITE buffer (ping-pong: no race
    // with other blocks' gemm reads of the READ buffer)
    {
        const int d = tid >> 2, q = tid & 3;
        const int mm0 = rowbase + q * 4;
        alignas(8) unsigned short hb4[4], lb4[4];
#pragma unroll
        for (int i = 0; i < 4; ++i) {
            float x = hnsh[q * 4 + i][d];
            unsigned short hh = f32_to_bf16(x);
            hb4[i] = hh;
            lb4[i] = f32_to_bf16(x - __uint_as_float((unsigned int)hh << 16));
        }
        unsigned short* dst = hThiW + ((size_t)(b * 64 + d)) * 1024 + mm0;
        *(uint2*)dst = *(const uint2*)hb4;
        unsigned short* dstl = hTloW + ((size_t)(b * 64 + d)) * 1024 + mm0;
        *(uint2*)dstl = *(const uint2*)lb4;
    }

    // ---- outk fused on the last step (hnsh still valid in LDS) ----
    if (last) {
#pragma unroll
        for (int i = 0; i < 4; ++i) {
            int nl = ng * 4 + i;
            int node = nodeBase + nl;
            float acc2 = o1b[j];
            for (int d2 = 0; d2 < 64; ++d2)
                acc2 = fmaf(hnsh[nl][d2], o1hT[d2 * 64 + j], acc2);
            const float* ap2 = ann + (size_t)node * 16;
#pragma unroll
            for (int a = 0; a < 16; ++a)
                acc2 = fmaf(ap2[a], o1aT[a * 64 + j], acc2);
            float t = ftanh(acc2) * o2W[j];
#pragma unroll
            for (int off = 32; off > 0; off >>= 1) t += __shfl_down(t, off);
            if (j == 0) out[node] = t + o2b[0];
        }
    }
}

// ---------------------------------------------------------------------------
extern "C" void kernel_launch(void* const* d_in, const int* in_sizes, int n_in,
                              void* d_out, int out_size, void* d_ws, size_t ws_size,
                              hipStream_t stream)
{
    (void)in_sizes; (void)n_in; (void)out_size; (void)ws_size;
    const float* prop = (const float*)d_in[0];
    const float* ann  = (const float*)d_in[1];
    const float* A    = (const float*)d_in[2];
    const float* inW  = (const float*)d_in[3];
    const float* inb  = (const float*)d_in[4];
    // d_in[5] out_W, d_in[6] out_b unused (a_out = a_in in the reference)
    const float* rW   = (const float*)d_in[7];
    const float* rb   = (const float*)d_in[8];
    const float* zW   = (const float*)d_in[9];
    const float* zb   = (const float*)d_in[10];
    const float* hW   = (const float*)d_in[11];
    const float* hb   = (const float*)d_in[12];
    const float* o1W  = (const float*)d_in[13];
    const float* o1b  = (const float*)d_in[14];
    const float* o2W  = (const float*)d_in[15];
    const float* o2b  = (const float*)d_in[16];
    float* out = (float*)d_out;

    // workspace layout (~74 MB of ~512 MiB)
    float* h_ws   = (float*)d_ws;                       // 262144
    float* wcomb  = h_ws + 262144;                      // 24576
    float* w1s    = wcomb + 24576;                      // 256
    float* o1hT   = w1s + 256;                          // 4096
    float* o1aT   = o1hT + 4096;                        // 1024
    float* rowsum = o1aT + 1024;                        // 16384
    unsigned short* Ahl   = (unsigned short*)(rowsum + 16384);  // 33554432
    unsigned short* hThi0 = Ahl + (size_t)33554432;             // 262144
    unsigned short* hTlo0 = hThi0 + 262144;
    unsigned short* hThi1 = hTlo0 + 262144;
    unsigned short* hTlo1 = hThi1 + 262144;

    prep<<<4096, 256, 0, stream>>>(A, prop, inW, rW, zW, hW, o1W,
                                   Ahl, rowsum, h_ws, hThi0, hTlo0,
                                   wcomb, w1s, o1hT, o1aT);

    for (int s = 0; s < STEPS; ++s) {
        const unsigned short* hr = (s & 1) ? hThi1 : hThi0;
        const unsigned short* lr = (s & 1) ? hTlo1 : hTlo0;
        unsigned short* hw = (s & 1) ? hThi0 : hThi1;
        unsigned short* lw = (s & 1) ? hTlo0 : hTlo1;
        step_k<<<dim3(64, 4), 256, 0, stream>>>(
            Ahl, hr, lr, w1s, rowsum, inb, wcomb, rb, zb, hb, h_ws,
            hw, lw, ann, o1hT, o1aT, o1b, o2W, o2b, out,
            (s == STEPS - 1) ? 1 : 0);
    }
}